// Round 5
// baseline (358.941 us; speedup 1.0000x reference)
//
#include <hip/hip_runtime.h>
#include <cfloat>

#define GT 16
#define NCLS 81
#define TPB 256
#define BPT 1024
#define MAXP 8732
#define TROWS 64
#define WF4 324              // float4 per wave slice: 16 rows * 81 / 4
#define TF4 (TROWS*NCLS/4)   // 1296 float4 per tile

__device__ __forceinline__ float smoothl1(float d){
  float a = fabsf(d);
  return a < 1.0f ? 0.5f*a*a : a - 0.5f;
}

// Kernel 1: per-(batch,gt) best prior via block-local reduction.
// One block per batch, 1024 threads; no global atomics. Fuses per-batch
// accumulator init.
__global__ __launch_bounds__(BPT) void bestprior(
    const float* __restrict__ priors,     // (P,4) xywh
    const float* __restrict__ gt_boxes,   // (B,GT,4) xyxy
    int*   __restrict__ best,             // (B,GT) prior index
    float* __restrict__ ce_pos, float* __restrict__ sl1_sum,
    int* __restrict__ num_pos, float* __restrict__ out, int P)
{
  const int b = blockIdx.x;
  const int tid = threadIdx.x, wave = tid >> 6, lane = tid & 63;
  __shared__ float gx0[GT], gy0[GT], gx1[GT], gy1[GT], ga[GT];
  __shared__ float redv[16*GT]; __shared__ int redi[16*GT];
  if (tid == 0){ ce_pos[b] = 0.0f; sl1_sum[b] = 0.0f; num_pos[b] = 0; }
  if (b == 0 && tid < 2) out[tid] = 0.0f;
  if (tid < GT){
    const float4 gb = ((const float4*)gt_boxes)[b*GT + tid];
    gx0[tid]=gb.x; gy0[tid]=gb.y; gx1[tid]=gb.z; gy1[tid]=gb.w;
    ga[tid] = (gb.z-gb.x)*(gb.w-gb.y);
  }
  __syncthreads();
  float bv[GT]; int bi[GT];
  #pragma unroll
  for (int g=0; g<GT; ++g){ bv[g] = -1.0f; bi[g] = 0x7fffffff; }
  for (int p = tid; p < P; p += BPT){          // ascending p per thread
    const float4 pr = ((const float4*)priors)[p];
    const float px0 = pr.x - pr.z*0.5f, py0 = pr.y - pr.w*0.5f;
    const float px1 = pr.x + pr.z*0.5f, py1 = pr.y + pr.w*0.5f;
    const float pa = (px1-px0)*(py1-py0);
    #pragma unroll
    for (int g=0; g<GT; ++g){
      const float w = fmaxf(fminf(gx1[g],px1) - fmaxf(gx0[g],px0), 0.0f);
      const float h = fmaxf(fminf(gy1[g],py1) - fmaxf(gy0[g],py0), 0.0f);
      const float inter = w*h;
      const float iou = inter / (ga[g] + pa - inter);
      if (iou > bv[g]){ bv[g] = iou; bi[g] = p; }   // first-max over p
    }
  }
  #pragma unroll
  for (int g=0; g<GT; ++g){
    float v = bv[g]; int i = bi[g];
    for (int off=32; off>0; off>>=1){
      const float ov = __shfl_down(v, off);
      const int   oi = __shfl_down(i, off);
      if (ov > v || (ov == v && oi < i)){ v = ov; i = oi; } // smaller p on tie
    }
    if (lane == 0){ redv[wave*GT+g] = v; redi[wave*GT+g] = i; }
  }
  __syncthreads();
  if (tid < GT){
    float v = redv[tid]; int i = redi[tid];
    for (int w=1; w<16; ++w){
      const float ov = redv[w*GT+tid]; const int oi = redi[w*GT+tid];
      if (ov > v || (ov == v && oi < i)){ v = ov; i = oi; }
    }
    best[b*GT + tid] = i;
  }
}

// Kernel 2: fused assign + barrier-free pipelined LSE.
// R5 change: the LSE inner loop had RUNTIME bounds (c0/c1 depend on q), so
// the compiler couldn't unroll it -> 21 serial {ds_read_b32; lgkmcnt(0);
// v_exp} trips at ~120cy single-outstanding LDS latency each (~2.6K
// serial cycles/iter). That latency chain -- present since R0's lse_pipe
// -- is why VALUBusy sat at 20-35% while HBM sat at 10%. Now a FIXED
// 21-trip #pragma unroll loop: 21 independent ds_reads batched under
// incremental lgkmcnt, then predicated exp-add (c<c1 ? exp : 0.0f) --
// bit-identical sum (same values, same ascending order). The q=3,j=20
// read of x[81] stays inside the +4-float LDS pad.
// NOTE: __launch_bounds__(TPB) ONLY -- a min-waves/EU clause (R2 tried 7)
// caps VGPRs at ~72 and spills the loop-carried prefetch regs: +570 MB HBM.
__global__ __launch_bounds__(TPB) void fused_lse(
    const float* __restrict__ priors,     // (P,4) xywh
    const float* __restrict__ gt_boxes,   // (B,GT,4) xyxy
    const int*   __restrict__ gt_labels,  // (B,GT)
    const float* __restrict__ box_reg,    // (B,P,4)
    const int*   __restrict__ best,       // (B,GT)
    const float* __restrict__ logits,     // (B*P, 81)
    float* __restrict__ bg,               // (B*P)
    float* __restrict__ ce_pos,           // (B)
    float* __restrict__ sl1_sum,          // (B)
    int*   __restrict__ num_pos,          // (B)
    int P, int NT)                        // NT = B*P/TROWS = 8732 exact
{
  __shared__ float s[TROWS*NCLS + 4];     // +4: pad for unconditional reads
  __shared__ float sgx0[2][GT], sgy0[2][GT], sgx1[2][GT], sgy1[2][GT], sga[2][GT];
  __shared__ int   slab[2][GT], sbp[2][GT];
  const int tid = threadIdx.x;
  const int wave = tid >> 6, lane = tid & 63;
  const int rl = lane >> 2, q = lane & 3;
  const int c0 = q ? (1+20*q) : 0;        // [0,21) [21,41) [41,61) [61,81)
  const int c1 = 21 + 20*q;
  const int G = gridDim.x;

  // contiguous tile range for this block
  const int qn = NT / G, rn = NT % G;
  const int k = blockIdx.x;
  const int t0  = k < rn ? k*(qn+1) : rn*(qn+1) + (k-rn)*qn;
  const int cnt = k < rn ? qn+1 : qn;
  if (cnt <= 0) return;
  const int tend = t0 + cnt;
  const int b0 = (t0*TROWS)/P;
  const int b1 = (tend*TROWS - 1)/P;      // <= b0+1 (cnt*64 << P)
  const int boundary = b1*P;              // row >= boundary -> slot 1

  if (tid < 2*GT){                        // stage gt data for both batches
    const int slot = tid >> 4, g = tid & 15;
    const int bb = slot ? b1 : b0;
    const float4 gb = ((const float4*)gt_boxes)[bb*GT + g];
    sgx0[slot][g]=gb.x; sgy0[slot][g]=gb.y; sgx1[slot][g]=gb.z; sgy1[slot][g]=gb.w;
    sga[slot][g] = (gb.z-gb.x)*(gb.w-gb.y);
    slab[slot][g] = gt_labels[bb*GT + g];
    sbp[slot][g]  = best[bb*GT + g];
  }
  __syncthreads();                        // one-time; loop stays barrier-free

  float4 r0,r1,r2,r3,r4,r5, prn, brn;
  auto load_logits = [&](int tt){
    const float4* src = (const float4*)logits + (long long)tt*TF4 + wave*WF4;
    r0 = src[lane]; r1 = src[lane+64]; r2 = src[lane+128];
    r3 = src[lane+192]; r4 = src[lane+256];
    if (lane < 4) r5 = src[lane+320];
  };
  auto load_row = [&](int tt){            // unconditional: no divergent loads
    const int rw = tt*TROWS + wave*16 + rl;
    const int bb = (rw >= boundary) ? b1 : b0;
    prn = ((const float4*)priors)[rw - bb*P];
    brn = ((const float4*)box_reg)[rw];
  };
  load_logits(t0); load_row(t0);

  float4* sd = (float4*)(s) + wave*WF4;
  const float* x = s + wave*(WF4*4) + rl*NCLS;
  for (int t = t0; t < tend; ++t){
    sd[lane] = r0; sd[lane+64] = r1; sd[lane+128] = r2;   // vmcnt drain point
    sd[lane+192] = r3; sd[lane+256] = r4;
    if (lane < 4) sd[lane+320] = r5;
    const float4 pr = prn, br = brn;      // copy BEFORE overwriting prefetch
    const int row = t*TROWS + wave*16 + rl;
    const int slot = (row >= boundary);
    const int b = slot ? b1 : b0;
    const int p = row - b*P;
    if (t+1 < tend){ load_logits(t+1); load_row(t+1); }   // stays in flight

    // ---- quad-parallel assignment (all 64 lanes useful) ----
    const float px0 = pr.x - pr.z*0.5f, py0 = pr.y - pr.w*0.5f;
    const float px1 = pr.x + pr.z*0.5f, py1 = pr.y + pr.w*0.5f;
    const float pa  = (px1-px0)*(py1-py0);
    float mv = -1.0f; int mi = 0;
    const int gbase = q*4;
    #pragma unroll
    for (int j=0; j<4; ++j){              // lane q covers g = 4q..4q+3
      const int g = gbase + j;
      const float w = fmaxf(fminf(sgx1[slot][g],px1) - fmaxf(sgx0[slot][g],px0), 0.0f);
      const float h = fmaxf(fminf(sgy1[slot][g],py1) - fmaxf(sgy0[slot][g],py0), 0.0f);
      const float inter = w*h;
      const float iou = inter / (sga[slot][g] + pa - inter);
      if (iou > mv){ mv = iou; mi = g; }  // first-max within lane (g asc)
    }
    #pragma unroll
    for (int m=1; m<4; m<<=1){            // quad argmax: tie -> smaller g
      const float omv = __shfl_xor(mv, m);
      const int   omi = __shfl_xor(mi, m);
      if (omv > mv || (omv == mv && omi < mi)){ mv = omv; mi = omi; }
    }
    int ov = -1;
    #pragma unroll
    for (int j=0; j<4; ++j){              // override scan, 4-way split
      const int g2 = gbase + j;
      if (sbp[slot][g2] == p) ov = g2;    // local last match
    }
    #pragma unroll
    for (int m=1; m<4; m<<=1) ov = max(ov, __shfl_xor(ov, m));
    if (ov >= 0){ mv = 2.0f; mi = ov; }   // last g wins (max g2)

    int lab = 0; float s1 = 0.0f;
    if (q == 0 && mv >= 0.5f){            // encode + SL1 (rare, q0 only)
      lab = slab[slot][mi];
      const float gbx0 = sgx0[slot][mi], gby0 = sgy0[slot][mi];
      const float gbx1 = sgx1[slot][mi], gby1 = sgy1[slot][mi];
      const float ctrx = (gbx0+gbx1)*0.5f, ctry = (gby0+gby1)*0.5f;
      const float wx = gbx1-gbx0, wy = gby1-gby0;
      const float tx = (ctrx - pr.x) / (0.1f*pr.z);
      const float ty = (ctry - pr.y) / (0.1f*pr.w);
      const float tw = __logf(wx/pr.z) / 0.2f;
      const float th = __logf(wy/pr.w) / 0.2f;
      s1 = smoothl1(br.x - tx) + smoothl1(br.y - ty)
         + smoothl1(br.z - tw) + smoothl1(br.w - th);
    }

    // ---- LSE over 81 classes: fixed 21-trip unrolled, predicated ----
    // 21 independent ds_read_b32 (imm offsets) batched under incremental
    // lgkmcnt, then exp + cndmask-add. Bit-identical to the runtime-bound
    // loop (adds +0.0f for masked trips, same ascending order).
    float sum = 0.0f;
    #pragma unroll
    for (int j = 0; j < 21; ++j){
      const int c = c0 + j;
      const float xv = x[c];              // unconditional; pad covers c=81
      sum += (c < c1) ? __expf(xv) : 0.0f;
    }
    sum += __shfl_xor(sum, 1);
    sum += __shfl_xor(sum, 2);
    if (q == 0){
      const float lse = __logf(sum);
      float bgv;
      if (lab > 0){
        atomicAdd(&ce_pos[b], lse - x[lab]);        // LDS gather, no vm wait
        atomicAdd(&sl1_sum[b], s1);                 // fire-and-forget, sparse
        atomicAdd(&num_pos[b], 1);
        bgv = 0.0f;
      } else {
        bgv = fmaxf(lse - x[0], 0.0f);              // clamp: radix needs >=0
      }
      bg[row] = bgv;
    }
  }
}

// Kernel 3: per-batch top-(3*num_pos) sum. Count-only 8-bit radix select
// (16 replicated histograms, stride 257 so replicas of a bin land in
// DIFFERENT banks), then one final pass sums values strictly above the
// threshold; ties contribute krem * threshold. Fused final /N reduce.
__global__ __launch_bounds__(TPB) void topk_kernel(
    const float* __restrict__ bg,
    const int*   __restrict__ num_pos,
    const float* __restrict__ sl1_sum,
    const float* __restrict__ ce_pos,
    float* __restrict__ out,
    int P, int B)
{
  const int b = blockIdx.x;
  const int tid = threadIdx.x;
  const int wave = tid >> 6, lane = tid & 63;
  const int rep = tid & 15;
  __shared__ float sv[MAXP];
  __shared__ unsigned cntR[16][257];    // padded: bank = (rep*257+bin)%32
  __shared__ unsigned s_wc[4];
  __shared__ float    s_wf[4];
  __shared__ unsigned s_prefix;
  __shared__ int s_krem, s_chosen, s_newk;

  {
    const float4* srcp = (const float4*)(bg + (long long)b * P);
    float4* dst = (float4*)sv;
    for (int j = tid; j < P/4; j += TPB) dst[j] = srcp[j];
  }
  if (tid == 0){
    const int k = 3*num_pos[b];
    s_krem = k < P ? k : P-1;
    s_prefix = 0u;
  }
  __syncthreads();

  for (int level=0; level<4; ++level){
    const int shift = 24 - 8*level;
    for (int i = tid; i < 16*257; i += TPB) ((unsigned*)cntR)[i] = 0u;
    __syncthreads();
    const unsigned pref = s_prefix;
    const int k = s_krem;
    for (int j = tid; j < P/4; j += TPB){
      const float4 f4 = ((const float4*)sv)[j];
      #pragma unroll
      for (int e=0; e<4; ++e){
        const unsigned key = __float_as_uint((&f4.x)[e]);
        const bool ok = (level == 0) || ((key >> (shift+8)) == pref);
        if (ok) atomicAdd(&cntR[rep][(key >> shift) & 255u], 1u);
      }
    }
    __syncthreads();
    const int rb = 255 - tid;
    unsigned c = 0;
    #pragma unroll
    for (int r=0; r<16; ++r) c += cntR[r][rb];
    unsigned cv = c;
    #pragma unroll
    for (int off=1; off<64; off<<=1){
      const unsigned oc = __shfl_up(cv, off);
      if (lane >= off) cv += oc;
    }
    if (lane == 63) s_wc[wave] = cv;
    __syncthreads();
    unsigned addc = 0;
    for (int w=0; w<4; ++w) if (w < wave) addc += s_wc[w];
    const unsigned S = cv - c + addc;   // count in bins > rb (matching prefix)
    if ((int)S <= k && k < (int)(S + c)){
      s_chosen = rb; s_newk = k - (int)S;      // exactly one thread
    }
    __syncthreads();
    if (tid == 0){
      s_krem = s_newk;
      s_prefix = (pref << 8) | (unsigned)s_chosen;
    }
    __syncthreads();
  }
  // final pass: sum of values strictly above threshold
  const unsigned T = s_prefix;
  float acc = 0.0f;
  for (int j = tid; j < P/4; j += TPB){
    const float4 f4 = ((const float4*)sv)[j];
    #pragma unroll
    for (int e=0; e<4; ++e){
      const float f = (&f4.x)[e];
      if (__float_as_uint(f) > T) acc += f;
    }
  }
  for (int off=32; off>0; off>>=1) acc += __shfl_down(acc, off);
  if (lane == 0) s_wf[wave] = acc;
  __syncthreads();
  if (tid < 64){                        // wave 0: N = sum(num_pos), /N shares
    float n = 0.0f;
    for (int i = tid; i < B; i += 64) n += (float)num_pos[i];
    for (int off=32; off>0; off>>=1) n += __shfl_down(n, off);
    if (tid == 0){
      const float N = n;
      const float cls = s_wf[0]+s_wf[1]+s_wf[2]+s_wf[3]
                      + (float)s_krem * __uint_as_float(T);
      atomicAdd(&out[0], sl1_sum[b] / N);
      atomicAdd(&out[1], (ce_pos[b] + cls) / N);
    }
  }
}

extern "C" void kernel_launch(void* const* d_in, const int* in_sizes, int n_in,
                              void* d_out, int out_size, void* d_ws, size_t ws_size,
                              hipStream_t stream) {
  const float* priors = (const float*)d_in[0];
  const float* logits = (const float*)d_in[1];
  const float* boxreg = (const float*)d_in[2];
  const float* gtb    = (const float*)d_in[3];
  const int*   gtl    = (const int*)d_in[4];
  const int P = in_sizes[0] / 4;          // 8732
  const int B = in_sizes[4] / GT;         // 64
  const long long BP = (long long)B * P;

  char* ws = (char*)d_ws;
  float* bgv  = (float*)ws;                             // BP float
  int*   best = (int*)(ws + BP*4);                      // B*GT int
  float* sl1_s= (float*)(ws + BP*4 + 4096);
  int*   npos = (int*)  (ws + BP*4 + 4352);
  float* cep  = (float*)(ws + BP*4 + 4608);

  bestprior<<<B, BPT, 0, stream>>>(priors, gtb, best, cep, sl1_s, npos,
                                   (float*)d_out, P);
  const int NT = (int)(BP / TROWS);       // 8732 exact
  const int G = 1792;                     // 7 blocks/CU (LDS ~21 KB)
  fused_lse<<<G, TPB, 0, stream>>>(priors, gtb, gtl, boxreg, best, logits,
                                   bgv, cep, sl1_s, npos, P, NT);
  topk_kernel<<<B, TPB, 0, stream>>>(bgv, npos, sl1_s, cep, (float*)d_out, P, B);
}

// Round 6
// 354.566 us; speedup vs baseline: 1.0123x; 1.0123x over previous
//
#include <hip/hip_runtime.h>
#include <cfloat>

#define GT 16
#define NCLS 81
#define TPB 256
#define BPT 1024
#define MAXP 8732
#define TROWS 64

__device__ __forceinline__ float smoothl1(float d){
  float a = fabsf(d);
  return a < 1.0f ? 0.5f*a*a : a - 0.5f;
}

// Kernel 1: per-(batch,gt) best prior via block-local reduction.
// One block per batch, 1024 threads; no global atomics. Fuses per-batch
// accumulator init.
__global__ __launch_bounds__(BPT) void bestprior(
    const float* __restrict__ priors,     // (P,4) xywh
    const float* __restrict__ gt_boxes,   // (B,GT,4) xyxy
    int*   __restrict__ best,             // (B,GT) prior index
    float* __restrict__ ce_pos, float* __restrict__ sl1_sum,
    int* __restrict__ num_pos, float* __restrict__ out, int P)
{
  const int b = blockIdx.x;
  const int tid = threadIdx.x, wave = tid >> 6, lane = tid & 63;
  __shared__ float gx0[GT], gy0[GT], gx1[GT], gy1[GT], ga[GT];
  __shared__ float redv[16*GT]; __shared__ int redi[16*GT];
  if (tid == 0){ ce_pos[b] = 0.0f; sl1_sum[b] = 0.0f; num_pos[b] = 0; }
  if (b == 0 && tid < 2) out[tid] = 0.0f;
  if (tid < GT){
    const float4 gb = ((const float4*)gt_boxes)[b*GT + tid];
    gx0[tid]=gb.x; gy0[tid]=gb.y; gx1[tid]=gb.z; gy1[tid]=gb.w;
    ga[tid] = (gb.z-gb.x)*(gb.w-gb.y);
  }
  __syncthreads();
  float bv[GT]; int bi[GT];
  #pragma unroll
  for (int g=0; g<GT; ++g){ bv[g] = -1.0f; bi[g] = 0x7fffffff; }
  for (int p = tid; p < P; p += BPT){          // ascending p per thread
    const float4 pr = ((const float4*)priors)[p];
    const float px0 = pr.x - pr.z*0.5f, py0 = pr.y - pr.w*0.5f;
    const float px1 = pr.x + pr.z*0.5f, py1 = pr.y + pr.w*0.5f;
    const float pa = (px1-px0)*(py1-py0);
    #pragma unroll
    for (int g=0; g<GT; ++g){
      const float w = fmaxf(fminf(gx1[g],px1) - fmaxf(gx0[g],px0), 0.0f);
      const float h = fmaxf(fminf(gy1[g],py1) - fmaxf(gy0[g],py0), 0.0f);
      const float inter = w*h;
      const float iou = inter / (ga[g] + pa - inter);
      if (iou > bv[g]){ bv[g] = iou; bi[g] = p; }   // first-max over p
    }
  }
  #pragma unroll
  for (int g=0; g<GT; ++g){
    float v = bv[g]; int i = bi[g];
    for (int off=32; off>0; off>>=1){
      const float ov = __shfl_down(v, off);
      const int   oi = __shfl_down(i, off);
      if (ov > v || (ov == v && oi < i)){ v = ov; i = oi; } // smaller p on tie
    }
    if (lane == 0){ redv[wave*GT+g] = v; redi[wave*GT+g] = i; }
  }
  __syncthreads();
  if (tid < GT){
    float v = redv[tid]; int i = redi[tid];
    for (int w=1; w<16; ++w){
      const float ov = redv[w*GT+tid]; const int oi = redi[w*GT+tid];
      if (ov > v || (ov == v && oi < i)){ v = ov; i = oi; }
    }
    best[b*GT + tid] = i;
  }
}

// Kernel 2: fused assign + LSE, DIRECT-GLOBAL (no logits LDS at all).
// R6 change: R0-R5 all staged each 64x81 tile through LDS (coalesced
// float4 loads -> ds_write -> ds_read transpose). That coupling (vmcnt
// drain at the store, lgkm wait before reads, single-buffer reuse, 22 KB
// LDS capping 7 blocks/CU) pinned the kernel at ~110 us across three
// successive VALU cuts (VALUBusy 35->18% with dur unchanged) -- the
// structure, not any instruction class, was the limiter.
// Now lane (rl,q) loads its OWN contiguous 84 B class-span [20q, 20q+20]
// of row rl straight from global (dword-aligned, LSV-vectorized, ~21
// outstanding loads/lane). The wave still touches exactly the 16 rows'
// 5.2 KB once (L1 lines shared across j). Re-basing at 20q and skipping
// the first element for q!=0 keeps the add sequence bit-identical
// (0+e0 == e0) and all addresses in [0,81). LDS drops to ~1 KB ->
// 8 blocks/CU; iterations fully decoupled.
// NOTE: __launch_bounds__(TPB) ONLY -- a min-waves/EU clause (R2 tried 7)
// caps VGPRs and spills: +570 MB HBM traffic.
__global__ __launch_bounds__(TPB) void fused_lse(
    const float* __restrict__ priors,     // (P,4) xywh
    const float* __restrict__ gt_boxes,   // (B,GT,4) xyxy
    const int*   __restrict__ gt_labels,  // (B,GT)
    const float* __restrict__ box_reg,    // (B,P,4)
    const int*   __restrict__ best,       // (B,GT)
    const float* __restrict__ logits,     // (B*P, 81)
    float* __restrict__ bg,               // (B*P)
    float* __restrict__ ce_pos,           // (B)
    float* __restrict__ sl1_sum,          // (B)
    int*   __restrict__ num_pos,          // (B)
    int P, int NT)                        // NT = B*P/TROWS = 8732 exact
{
  __shared__ float sgx0[2][GT], sgy0[2][GT], sgx1[2][GT], sgy1[2][GT], sga[2][GT];
  __shared__ int   slab[2][GT], sbp[2][GT];
  const int tid = threadIdx.x;
  const int wave = tid >> 6, lane = tid & 63;
  const int rl = lane >> 2, q = lane & 3;
  const int G = gridDim.x;

  // contiguous tile range for this block (<= 2 batches: span <= 320 rows)
  const int qn = NT / G, rn = NT % G;
  const int k = blockIdx.x;
  const int t0  = k < rn ? k*(qn+1) : rn*(qn+1) + (k-rn)*qn;
  const int cnt = k < rn ? qn+1 : qn;
  if (cnt <= 0) return;
  const int tend = t0 + cnt;
  const int b0 = (t0*TROWS)/P;
  const int b1 = (tend*TROWS - 1)/P;      // <= b0+1
  const int boundary = b1*P;              // row >= boundary -> slot 1

  if (tid < 2*GT){                        // stage gt data for both batches
    const int slot = tid >> 4, g = tid & 15;
    const int bb = slot ? b1 : b0;
    const float4 gb = ((const float4*)gt_boxes)[bb*GT + g];
    sgx0[slot][g]=gb.x; sgy0[slot][g]=gb.y; sgx1[slot][g]=gb.z; sgy1[slot][g]=gb.w;
    sga[slot][g] = (gb.z-gb.x)*(gb.w-gb.y);
    slab[slot][g] = gt_labels[bb*GT + g];
    sbp[slot][g]  = best[bb*GT + g];
  }
  __syncthreads();                        // one-time; loop is barrier-free

  const int s = q*20;                     // class-span base: 0/20/40/60
  for (int t = t0; t < tend; ++t){
    const int row = t*TROWS + wave*16 + rl;
    const int slot = (row >= boundary);
    const int b = slot ? b1 : b0;
    const int p = row - b*P;
    const float* xr = logits + (long long)row*NCLS;

    // 21 contiguous dword loads (LSV merges to dwordx4/x2; ~6 VMEM ops,
    // all independent -> deep MLP). Max index s+20 = 80 < 81: no OOB.
    float xv[21];
    #pragma unroll
    for (int j = 0; j < 21; ++j) xv[j] = xr[s + j];

    const float4 pr = ((const float4*)priors)[p];
    const float4 br = ((const float4*)box_reg)[row];

    // ---- quad-parallel assignment (all 64 lanes useful) ----
    const float px0 = pr.x - pr.z*0.5f, py0 = pr.y - pr.w*0.5f;
    const float px1 = pr.x + pr.z*0.5f, py1 = pr.y + pr.w*0.5f;
    const float pa  = (px1-px0)*(py1-py0);
    float mv = -1.0f; int mi = 0;
    const int gbase = q*4;
    #pragma unroll
    for (int j=0; j<4; ++j){              // lane q covers g = 4q..4q+3
      const int g = gbase + j;
      const float w = fmaxf(fminf(sgx1[slot][g],px1) - fmaxf(sgx0[slot][g],px0), 0.0f);
      const float h = fmaxf(fminf(sgy1[slot][g],py1) - fmaxf(sgy0[slot][g],py0), 0.0f);
      const float inter = w*h;
      const float iou = inter / (sga[slot][g] + pa - inter);
      if (iou > mv){ mv = iou; mi = g; }  // first-max within lane (g asc)
    }
    #pragma unroll
    for (int m=1; m<4; m<<=1){            // quad argmax: tie -> smaller g
      const float omv = __shfl_xor(mv, m);
      const int   omi = __shfl_xor(mi, m);
      if (omv > mv || (omv == mv && omi < mi)){ mv = omv; mi = omi; }
    }
    int ov = -1;
    #pragma unroll
    for (int j=0; j<4; ++j){              // override scan, 4-way split
      const int g2 = gbase + j;
      if (sbp[slot][g2] == p) ov = g2;    // local last match
    }
    #pragma unroll
    for (int m=1; m<4; m<<=1) ov = max(ov, __shfl_xor(ov, m));
    if (ov >= 0){ mv = 2.0f; mi = ov; }   // last g wins (max g2)

    int lab = 0; float s1 = 0.0f;
    if (q == 0 && mv >= 0.5f){            // encode + SL1 (rare, q0 only)
      lab = slab[slot][mi];
      const float gbx0 = sgx0[slot][mi], gby0 = sgy0[slot][mi];
      const float gbx1 = sgx1[slot][mi], gby1 = sgy1[slot][mi];
      const float ctrx = (gbx0+gbx1)*0.5f, ctry = (gby0+gby1)*0.5f;
      const float wx = gbx1-gbx0, wy = gby1-gby0;
      const float tx = (ctrx - pr.x) / (0.1f*pr.z);
      const float ty = (ctry - pr.y) / (0.1f*pr.w);
      const float tw = __logf(wx/pr.z) / 0.2f;
      const float th = __logf(wy/pr.w) / 0.2f;
      s1 = smoothl1(br.x - tx) + smoothl1(br.y - ty)
         + smoothl1(br.z - tw) + smoothl1(br.w - th);
    }

    // ---- LSE: ascending add sequence, bit-identical to prior rounds ----
    // q==0 sums c=0..20; q>0 skips xv[0] (c=20q) and sums c=20q+1..20q+20.
    float sum = (q == 0) ? __expf(xv[0]) : 0.0f;
    #pragma unroll
    for (int j = 1; j < 21; ++j) sum += __expf(xv[j]);
    sum += __shfl_xor(sum, 1);
    sum += __shfl_xor(sum, 2);
    if (q == 0){
      const float lse = __logf(sum);
      float bgv;
      if (lab > 0){
        atomicAdd(&ce_pos[b], lse - xr[lab]);       // L1-hot gather, rare
        atomicAdd(&sl1_sum[b], s1);
        atomicAdd(&num_pos[b], 1);
        bgv = 0.0f;
      } else {
        bgv = fmaxf(lse - xv[0], 0.0f);             // clamp: radix needs >=0
      }
      bg[row] = bgv;
    }
  }
}

// Kernel 3: per-batch top-(3*num_pos) sum. Count-only 8-bit radix select
// (16 replicated histograms, stride 257 so replicas of a bin land in
// DIFFERENT banks), then one final pass sums values strictly above the
// threshold; ties contribute krem * threshold. Fused final /N reduce.
__global__ __launch_bounds__(TPB) void topk_kernel(
    const float* __restrict__ bg,
    const int*   __restrict__ num_pos,
    const float* __restrict__ sl1_sum,
    const float* __restrict__ ce_pos,
    float* __restrict__ out,
    int P, int B)
{
  const int b = blockIdx.x;
  const int tid = threadIdx.x;
  const int wave = tid >> 6, lane = tid & 63;
  const int rep = tid & 15;
  __shared__ float sv[MAXP];
  __shared__ unsigned cntR[16][257];    // padded: bank = (rep*257+bin)%32
  __shared__ unsigned s_wc[4];
  __shared__ float    s_wf[4];
  __shared__ unsigned s_prefix;
  __shared__ int s_krem, s_chosen, s_newk;

  {
    const float4* srcp = (const float4*)(bg + (long long)b * P);
    float4* dst = (float4*)sv;
    for (int j = tid; j < P/4; j += TPB) dst[j] = srcp[j];
  }
  if (tid == 0){
    const int k = 3*num_pos[b];
    s_krem = k < P ? k : P-1;
    s_prefix = 0u;
  }
  __syncthreads();

  for (int level=0; level<4; ++level){
    const int shift = 24 - 8*level;
    for (int i = tid; i < 16*257; i += TPB) ((unsigned*)cntR)[i] = 0u;
    __syncthreads();
    const unsigned pref = s_prefix;
    const int k = s_krem;
    for (int j = tid; j < P/4; j += TPB){
      const float4 f4 = ((const float4*)sv)[j];
      #pragma unroll
      for (int e=0; e<4; ++e){
        const unsigned key = __float_as_uint((&f4.x)[e]);
        const bool ok = (level == 0) || ((key >> (shift+8)) == pref);
        if (ok) atomicAdd(&cntR[rep][(key >> shift) & 255u], 1u);
      }
    }
    __syncthreads();
    const int rb = 255 - tid;
    unsigned c = 0;
    #pragma unroll
    for (int r=0; r<16; ++r) c += cntR[r][rb];
    unsigned cv = c;
    #pragma unroll
    for (int off=1; off<64; off<<=1){
      const unsigned oc = __shfl_up(cv, off);
      if (lane >= off) cv += oc;
    }
    if (lane == 63) s_wc[wave] = cv;
    __syncthreads();
    unsigned addc = 0;
    for (int w=0; w<4; ++w) if (w < wave) addc += s_wc[w];
    const unsigned S = cv - c + addc;   // count in bins > rb (matching prefix)
    if ((int)S <= k && k < (int)(S + c)){
      s_chosen = rb; s_newk = k - (int)S;      // exactly one thread
    }
    __syncthreads();
    if (tid == 0){
      s_krem = s_newk;
      s_prefix = (pref << 8) | (unsigned)s_chosen;
    }
    __syncthreads();
  }
  // final pass: sum of values strictly above threshold
  const unsigned T = s_prefix;
  float acc = 0.0f;
  for (int j = tid; j < P/4; j += TPB){
    const float4 f4 = ((const float4*)sv)[j];
    #pragma unroll
    for (int e=0; e<4; ++e){
      const float f = (&f4.x)[e];
      if (__float_as_uint(f) > T) acc += f;
    }
  }
  for (int off=32; off>0; off>>=1) acc += __shfl_down(acc, off);
  if (lane == 0) s_wf[wave] = acc;
  __syncthreads();
  if (tid < 64){                        // wave 0: N = sum(num_pos), /N shares
    float n = 0.0f;
    for (int i = tid; i < B; i += 64) n += (float)num_pos[i];
    for (int off=32; off>0; off>>=1) n += __shfl_down(n, off);
    if (tid == 0){
      const float N = n;
      const float cls = s_wf[0]+s_wf[1]+s_wf[2]+s_wf[3]
                      + (float)s_krem * __uint_as_float(T);
      atomicAdd(&out[0], sl1_sum[b] / N);
      atomicAdd(&out[1], (ce_pos[b] + cls) / N);
    }
  }
}

extern "C" void kernel_launch(void* const* d_in, const int* in_sizes, int n_in,
                              void* d_out, int out_size, void* d_ws, size_t ws_size,
                              hipStream_t stream) {
  const float* priors = (const float*)d_in[0];
  const float* logits = (const float*)d_in[1];
  const float* boxreg = (const float*)d_in[2];
  const float* gtb    = (const float*)d_in[3];
  const int*   gtl    = (const int*)d_in[4];
  const int P = in_sizes[0] / 4;          // 8732
  const int B = in_sizes[4] / GT;         // 64
  const long long BP = (long long)B * P;

  char* ws = (char*)d_ws;
  float* bgv  = (float*)ws;                             // BP float
  int*   best = (int*)(ws + BP*4);                      // B*GT int
  float* sl1_s= (float*)(ws + BP*4 + 4096);
  int*   npos = (int*)  (ws + BP*4 + 4352);
  float* cep  = (float*)(ws + BP*4 + 4608);

  bestprior<<<B, BPT, 0, stream>>>(priors, gtb, best, cep, sl1_s, npos,
                                   (float*)d_out, P);
  const int NT = (int)(BP / TROWS);       // 8732 exact
  const int G = 2048;                     // 8 blocks/CU (LDS ~1 KB now)
  fused_lse<<<G, TPB, 0, stream>>>(priors, gtb, gtl, boxreg, best, logits,
                                   bgv, cep, sl1_s, npos, P, NT);
  topk_kernel<<<B, TPB, 0, stream>>>(bgv, npos, sl1_s, cep, (float*)d_out, P, B);
}